// Round 1
// baseline (90.517 us; speedup 1.0000x reference)
//
#include <hip/hip_runtime.h>

// CRF loss on MI355X.
// Algorithm:
//   Z-part: exp-domain forward algorithm. exp(step matrix) = diag(g_t)*E with
//   g_t[i]=exp(sigmoid(h[t,b,i])), E=exp(trans)*2^-4 (per-step scale, corrected
//   by 4*ln2*len[b] at the end). L=1024 split into 16 chunks of 64 steps;
//   phase 1: one wave per (b,chunk) builds P_chunk via chained
//   v_mfma_f32_16x16x16_bf16 (D->next B operand is an identity lane mapping).
//   phase 2: one wave per b combines 16 chunk matrices by matvec with
//   per-chunk power-of-2 renormalization (exact log2 bookkeeping).
//   S-part: gather-sum of trans[y0[t+1],y0[t]]*mask[t] (+ trans[PAD,y0[len]]).
// ws layout: [0,8KB) len (f32/b), [8KB,16KB) S (f32/b), [16KB, +16MB) P bf16.
// ws required: 16KB + 2048*16*512B = ~16.8MB.

typedef unsigned int u32;
typedef float f32x4 __attribute__((ext_vector_type(4)));
typedef short s16x4 __attribute__((ext_vector_type(4)));
typedef unsigned int u32x2 __attribute__((ext_vector_type(2)));

#define LOG2E 1.4426950408889634f
#define LN2   0.6931471805599453f
#define Bsz   2048
#define Lsz   1024

#if __has_builtin(__builtin_amdgcn_exp2f)
__device__ __forceinline__ float exp2x(float x){ return __builtin_amdgcn_exp2f(x); }
#else
__device__ __forceinline__ float exp2x(float x){ return exp2f(x); }
#endif
#if __has_builtin(__builtin_amdgcn_logf)
__device__ __forceinline__ float log2x(float x){ return __builtin_amdgcn_logf(x); }
#else
__device__ __forceinline__ float log2x(float x){ return log2f(x); }
#endif
#if __has_builtin(__builtin_amdgcn_rcpf)
__device__ __forceinline__ float rcpx(float x){ return __builtin_amdgcn_rcpf(x); }
#else
__device__ __forceinline__ float rcpx(float x){ return 1.0f/x; }
#endif

__device__ __forceinline__ u32 cvtpk_bf16(float lo, float hi){
  u32 r;
  asm("v_cvt_pk_bf16_f32 %0, %1, %2" : "=v"(r) : "v"(lo), "v"(hi));
  return r;
}

// Inline-asm MFMA with conservative hazard padding (compiler can't see asm
// hazards: s_nop 1 before covers VALU-write->MFMA-read; 2x s_nop 7 after
// covers MFMA-write->VALU-read for a 4-pass MFMA).
__device__ __forceinline__ f32x4 mfma_16x16x16_bf16(s16x4 a, s16x4 b, f32x4 c){
  f32x4 d;
  asm volatile("s_nop 1\n\t"
      "v_mfma_f32_16x16x16_bf16 %0, %1, %2, %3\n\t"
      "s_nop 7\n\t"
      "s_nop 7"
      : "=&v"(d) : "v"(a), "v"(b), "v"(c));
  return d;
}

__global__ __launch_bounds__(256) void k_zero(float* lenw, float* Sw, float* out){
  int i = blockIdx.x*256 + threadIdx.x;
  if (i < Bsz) lenw[i] = 0.f;
  else if (i < 2*Bsz) Sw[i - Bsz] = 0.f;
  if (i == 0) out[0] = 0.f;
}

// lengths[b] = sum_t mask[t,b]; S[b] partial = sum_t trans[y0[t+1],y0[t]]*mask[t] (t<=1022)
__global__ __launch_bounds__(256) void k_score(const int* __restrict__ y0,
    const float* __restrict__ mask, const float* __restrict__ trans,
    float* __restrict__ lenw, float* __restrict__ Sw){
  __shared__ float Tt[256];
  Tt[threadIdx.x] = trans[threadIdx.x];
  __syncthreads();
  int gid = blockIdx.x*256 + threadIdx.x;   // 65536 threads: b fast, tc slow
  int b  = gid & (Bsz-1);
  int tc = gid >> 11;                        // 0..31, 32 t's each
  int t0 = tc * 32;
  float lacc = 0.f, sacc = 0.f;
  int yc = y0[t0*Bsz + b];
  #pragma unroll 4
  for (int t = t0; t < t0+32; ++t) {
    float m = mask[t*Bsz + b];
    int yn = y0[(t+1)*Bsz + b];
    lacc += m;
    if (t <= Lsz-2) sacc += m * Tt[yn*16 + yc];
    yc = yn;
  }
  atomicAdd(&lenw[b], lacc);
  atomicAdd(&Sw[b], sacc);
}

// Phase 1: wave per (b, chunk). P = Em_{last}...Em_{first} in exp domain, bf16.
__global__ __launch_bounds__(256) void k_phase1(const float* __restrict__ h,
    const float* __restrict__ trans, const float* __restrict__ lenw,
    u32x2* __restrict__ Pout){
  int wid = blockIdx.x*4 + (threadIdx.x >> 6);
  int c   = wid >> 11;          // 0..15 chunk
  int b   = wid & (Bsz-1);
  int lane = threadIdx.x & 63;
  int cl  = lane & 15;          // A-row / B-col / D-col
  int grp = lane >> 4;          // 0..3
  int len = (int)(lenw[b] + 0.5f);
  int t0  = c << 6;
  int active = len - t0;
  if (active <= 0) return;      // chunk fully masked: phase 2 skips it
  if (active > 64) active = 64;

  // E row cl, k-cols grp*4..+3, scaled by 2^-4. exp(NEG) underflows to exact 0.
  const float* tp = trans + cl*16 + grp*4;
  float E0 = exp2x(tp[0]*LOG2E) * 0.0625f;
  float E1 = exp2x(tp[1]*LOG2E) * 0.0625f;
  float E2 = exp2x(tp[2]*LOG2E) * 0.0625f;
  float E3 = exp2x(tp[3]*LOG2E) * 0.0625f;

  // B operand = identity (bf16 1.0 = 0x3F80)
  int k0 = grp*4;
  u32 bx = ((k0+0)==cl ? 0x3F80u : 0u) | (((k0+1)==cl ? 0x3F80u : 0u) << 16);
  u32 by = ((k0+2)==cl ? 0x3F80u : 0u) | (((k0+3)==cl ? 0x3F80u : 0u) << 16);

  f32x4 zero4 = {0.f, 0.f, 0.f, 0.f};
  // lane loads h[t0 + 4r + grp, b, cl] : one dword covers 4 steps per wave
  const float* hp = h + (size_t)(t0+grp)*(Bsz*16) + b*16 + cl;
  int a_addr0 = (cl      ) << 2;
  int a_addr1 = (cl | 16 ) << 2;
  int a_addr2 = (cl | 32 ) << 2;
  int a_addr3 = (cl | 48 ) << 2;

  for (int r = 0; r < 16; ++r) {
    int sb = r*4;
    if (sb >= active) break;
    float hv = *hp; hp += 4*(Bsz*16);
    // g = exp(sigmoid(hv)) = exp2(sigmoid(hv)*log2e)
    float sg = rcpx(1.f + exp2x(hv * (-LOG2E)));
    float gv = exp2x(sg * LOG2E);
    int gvi = __float_as_int(gv);
    #pragma unroll
    for (int q = 0; q < 4; ++q) {
      if (sb + q >= active) break;
      int aaddr = (q==0) ? a_addr0 : (q==1) ? a_addr1 : (q==2) ? a_addr2 : a_addr3;
      float gq = __int_as_float(__builtin_amdgcn_ds_bpermute(aaddr, gvi));
      union { u32 u[2]; s16x4 v; } A, Bf;
      A.u[0] = cvtpk_bf16(gq*E0, gq*E1);
      A.u[1] = cvtpk_bf16(gq*E2, gq*E3);
      Bf.u[0] = bx; Bf.u[1] = by;
      f32x4 d = mfma_16x16x16_bf16(A.v, Bf.v, zero4);
      // D -> next B: identity lane/element mapping, just convert to bf16
      bx = cvtpk_bf16(d.x, d.y);
      by = cvtpk_bf16(d.z, d.w);
    }
  }
  Pout[(size_t)(b*16 + c)*64 + lane] = (u32x2){bx, by};
}

// Phase 2: wave per b. v <- P_c * v with power-of-2 renorm; then final lse.
__global__ __launch_bounds__(256) void k_phase2(const u32x2* __restrict__ P,
    const float* __restrict__ trans, const float* __restrict__ lenw,
    const float* __restrict__ Sw, const int* __restrict__ y0,
    float* __restrict__ out){
  __shared__ float red[4];
  int b = blockIdx.x*4 + (threadIdx.x >> 6);
  int lane = threadIdx.x & 63;
  int cl = lane & 15, grp = lane >> 4;
  int len = (int)(lenw[b] + 0.5f);
  float v = (cl == 1) ? 1.f : 0.f;    // exp(Z0): one-hot at SOS_IDX=1
  float lsc = 0.f;                    // accumulated log2 scale
  int nch = (len + 63) >> 6;
  const u32x2* Pb = P + (size_t)b*16*64;
  int srcaddr = (cl >> 2) << 6;       // bpermute byte addr of lane (cl>>2)*16
  int msel = cl & 3;
  for (int c = 0; c < nch; ++c) {
    u32x2 pw = Pb[c*64 + lane];       // P[grp*4+m, cl] bf16 pairs
    float p0 = __uint_as_float(pw.x << 16);
    float p1 = __uint_as_float(pw.x & 0xffff0000u);
    float p2 = __uint_as_float(pw.y << 16);
    float p3 = __uint_as_float(pw.y & 0xffff0000u);
    float q0 = p0*v, q1 = p1*v, q2 = p2*v, q3 = p3*v;
    #pragma unroll
    for (int mk = 1; mk <= 8; mk <<= 1) {
      q0 += __shfl_xor(q0, mk);
      q1 += __shfl_xor(q1, mk);
      q2 += __shfl_xor(q2, mk);
      q3 += __shfl_xor(q3, mk);
    }
    // q_m = v'[grp*4+m]; rebuild v = v'[cl]
    float t0v = __int_as_float(__builtin_amdgcn_ds_bpermute(srcaddr, __float_as_int(q0)));
    float t1v = __int_as_float(__builtin_amdgcn_ds_bpermute(srcaddr, __float_as_int(q1)));
    float t2v = __int_as_float(__builtin_amdgcn_ds_bpermute(srcaddr, __float_as_int(q2)));
    float t3v = __int_as_float(__builtin_amdgcn_ds_bpermute(srcaddr, __float_as_int(q3)));
    float vn = (msel==0) ? t0v : (msel==1) ? t1v : (msel==2) ? t2v : t3v;
    // renorm by 2^-eb, eb = exponent(max)
    float gm = fmaxf(fmaxf(q0,q1), fmaxf(q2,q3));
    gm = fmaxf(gm, __shfl_xor(gm, 16));
    gm = fmaxf(gm, __shfl_xor(gm, 32));
    int eb = (int)((__float_as_uint(gm) >> 23) & 0xff) - 127;
    float sc = __uint_as_float((u32)(127 - eb) << 23);
    v = vn * sc;
    lsc += (float)eb;
  }
  // final: lse_i(Z[i] + trans[EOS,i]) ; EOS row = trans[32+i]
  float eE = exp2x(trans[32 + cl] * LOG2E);
  float num = v * eE;
  num += __shfl_xor(num, 1);
  num += __shfl_xor(num, 2);
  num += __shfl_xor(num, 4);
  num += __shfl_xor(num, 8);
  if (lane == 0) {
    // undo: per-active-step 2^-4 (total 4*len in log2) + renorm scales
    float Z = (log2x(num) + lsc + 4.f*(float)len) * LN2;
    int lastTag = y0[(size_t)len*Bsz + b];
    float Sb = Sw[b] + trans[lastTag];     // trans[PAD=0, lastTag]
    red[threadIdx.x >> 6] = (Z - Sb) * (1.f/(float)Bsz);
  }
  __syncthreads();
  if (threadIdx.x == 0) {
    atomicAdd(out, red[0] + red[1] + red[2] + red[3]);
  }
}

extern "C" void kernel_launch(void* const* d_in, const int* in_sizes, int n_in,
                              void* d_out, int out_size, void* d_ws, size_t ws_size,
                              hipStream_t stream) {
  const float* h     = (const float*)d_in[0];
  const int*   y0    = (const int*)d_in[1];
  const float* mask  = (const float*)d_in[2];
  const float* trans = (const float*)d_in[3];
  float* out  = (float*)d_out;
  float* lenw = (float*)d_ws;
  float* Sw   = lenw + Bsz;
  u32x2* P    = (u32x2*)((char*)d_ws + 16384);

  k_zero  <<<16,   256, 0, stream>>>(lenw, Sw, out);
  k_score <<<256,  256, 0, stream>>>(y0, mask, trans, lenw, Sw);
  k_phase1<<<8192, 256, 0, stream>>>(h, trans, lenw, P);
  k_phase2<<<512,  256, 0, stream>>>(P, trans, lenw, Sw, y0, out);
}

// Round 3
// 81.354 us; speedup vs baseline: 1.1126x; 1.1126x over previous
//
#include <hip/hip_runtime.h>

// CRF loss on MI355X.
// Algorithm:
//   Z-part: exp-domain forward algorithm. exp(step matrix) = diag(g_t)*E with
//   g_t[i]=exp(sigmoid(h[t,b,i])), E=exp(trans)*2^-4 (per-step scale, corrected
//   by 4*ln2*len[b] at the end). L=1024 split into 16 chunks of 64 steps;
//   phase 1: one wave per (b,chunk) builds P_chunk via chained
//   v_mfma_f32_16x16x16_bf16 (D->next B operand is an identity lane mapping).
//   phase 2: one wave per b combines 16 chunk matrices by matvec with
//   per-chunk power-of-2 renormalization (exact log2 bookkeeping).
//   S-part: gather-sum of trans[y0[t+1],y0[t]]*mask[t] (+ trans[PAD,y0[len]]).
// R3 changes vs R1 (78us phase1 = DS-pipe-bound: 4 ds_bpermute per step):
//   - stage g into per-wave LDS tile TRANSPOSED gT[cl][t] (padded rows), so a
//     quad of 4 steps needs one ds_read_b128 instead of 4 ds_bpermute
//     (16x fewer DS-pipe ops). Staging is coalesced; sigmoid/exp computed once.
//   - MFMA stays the R1-proven asm volatile version (R2's builtin NaN'd).
//   - k_zero/k_score/k_phase2 identical to R1 (proven, not the bottleneck).
// ws layout: [0,8KB) len (f32/b), [8KB,16KB) S (f32/b), [16KB, +16MB) P bf16.

typedef unsigned int u32;
typedef float f32x4 __attribute__((ext_vector_type(4)));
typedef short s16x4 __attribute__((ext_vector_type(4)));
typedef unsigned int u32x2 __attribute__((ext_vector_type(2)));

#define LOG2E 1.4426950408889634f
#define LN2   0.6931471805599453f
#define Bsz   2048
#define Lsz   1024
#define BT    32768   /* Bsz*16 floats per timestep */

#if __has_builtin(__builtin_amdgcn_exp2f)
__device__ __forceinline__ float exp2x(float x){ return __builtin_amdgcn_exp2f(x); }
#else
__device__ __forceinline__ float exp2x(float x){ return exp2f(x); }
#endif
#if __has_builtin(__builtin_amdgcn_logf)
__device__ __forceinline__ float log2x(float x){ return __builtin_amdgcn_logf(x); }
#else
__device__ __forceinline__ float log2x(float x){ return log2f(x); }
#endif
#if __has_builtin(__builtin_amdgcn_rcpf)
__device__ __forceinline__ float rcpx(float x){ return __builtin_amdgcn_rcpf(x); }
#else
__device__ __forceinline__ float rcpx(float x){ return 1.0f/x; }
#endif

__device__ __forceinline__ u32 cvtpk_bf16(float lo, float hi){
  u32 r;
  asm("v_cvt_pk_bf16_f32 %0, %1, %2" : "=v"(r) : "v"(lo), "v"(hi));
  return r;
}

// R1-proven inline-asm MFMA with conservative hazard padding.
__device__ __forceinline__ f32x4 mfma16(s16x4 a, s16x4 b, f32x4 c){
  f32x4 d;
  asm volatile("s_nop 1\n\t"
      "v_mfma_f32_16x16x16_bf16 %0, %1, %2, %3\n\t"
      "s_nop 7\n\t"
      "s_nop 7"
      : "=&v"(d) : "v"(a), "v"(b), "v"(c));
  return d;
}

__global__ __launch_bounds__(256) void k_zero(float* lenw, float* Sw, float* out){
  int i = blockIdx.x*256 + threadIdx.x;
  if (i < Bsz) lenw[i] = 0.f;
  else if (i < 2*Bsz) Sw[i - Bsz] = 0.f;
  if (i == 0) out[0] = 0.f;
}

// lengths[b] = sum_t mask[t,b]; S[b] partial = sum_t trans[y0[t+1],y0[t]]*mask[t] (t<=1022)
__global__ __launch_bounds__(256) void k_score(const int* __restrict__ y0,
    const float* __restrict__ mask, const float* __restrict__ trans,
    float* __restrict__ lenw, float* __restrict__ Sw){
  __shared__ float Tt[256];
  Tt[threadIdx.x] = trans[threadIdx.x];
  __syncthreads();
  int gid = blockIdx.x*256 + threadIdx.x;   // 65536 threads: b fast, tc slow
  int b  = gid & (Bsz-1);
  int tc = gid >> 11;                        // 0..31, 32 t's each
  int t0 = tc * 32;
  float lacc = 0.f, sacc = 0.f;
  int yc = y0[t0*Bsz + b];
  #pragma unroll 4
  for (int t = t0; t < t0+32; ++t) {
    float m = mask[t*Bsz + b];
    int yn = y0[(t+1)*Bsz + b];
    lacc += m;
    if (t <= Lsz-2) sacc += m * Tt[yn*16 + yc];
    yc = yn;
  }
  atomicAdd(&lenw[b], lacc);
  atomicAdd(&Sw[b], sacc);
}

// Phase 1: wave per (b, chunk). P = Em_{last}...Em_{first} in exp domain, bf16.
__global__ __launch_bounds__(256) void k_phase1(const float* __restrict__ h,
    const float* __restrict__ trans, const float* __restrict__ lenw,
    u32x2* __restrict__ Pout){
  // per-warp transposed g tile: gT[warp][cl][t], row padded to 68 dwords
  // (bank(cl*68+t) = (4*cl + t) & 31 -> max 2-way aliasing, free).
  __shared__ float gT[4][16][68];
  int warp = threadIdx.x >> 6;
  int wid  = blockIdx.x*4 + warp;
  int c    = wid >> 11;          // 0..15 chunk
  int b    = wid & (Bsz-1);
  int lane = threadIdx.x & 63;
  int cl   = lane & 15;          // A-row / B-col / D-col
  int grp  = lane >> 4;          // 0..3
  int len = (int)(lenw[b] + 0.5f);
  int t0  = c << 6;
  int active = len - t0;
  if (active <= 0) return;      // chunk fully masked: phase 2 skips it
  if (active > 64) active = 64;

  // ---- stage g = exp(sigmoid(h)) for the whole 64-step chunk (always in
  // bounds: t0+63 <= 1023). Lane (grp,cl) handles t = 4i+grp, own tag cl.
  {
    const float* hp = h + (size_t)(t0 + grp)*BT + b*16 + cl;
    #pragma unroll
    for (int i = 0; i < 16; ++i) {
      float hv = hp[(size_t)(4*i)*BT];
      float sg = rcpx(1.f + exp2x(hv * (-LOG2E)));
      gT[warp][cl][4*i + grp] = exp2x(sg * LOG2E);
    }
  }

  // E row cl, k-cols grp*4..+3, scaled by 2^-4. exp(NEG) underflows to exact 0.
  const float* tp = trans + cl*16 + grp*4;
  float E0 = exp2x(tp[0]*LOG2E) * 0.0625f;
  float E1 = exp2x(tp[1]*LOG2E) * 0.0625f;
  float E2 = exp2x(tp[2]*LOG2E) * 0.0625f;
  float E3 = exp2x(tp[3]*LOG2E) * 0.0625f;

  // Running product B operand, init = identity (bf16 1.0 = 0x3F80)
  int k0 = grp*4;
  u32 bx = ((k0+0)==cl ? 0x3F80u : 0u) | (((k0+1)==cl ? 0x3F80u : 0u) << 16);
  u32 by = ((k0+2)==cl ? 0x3F80u : 0u) | (((k0+3)==cl ? 0x3F80u : 0u) << 16);

  const f32x4 zero4 = {0.f, 0.f, 0.f, 0.f};

#define STEP(GQ) do {                                                      \
    union { u32 u[2]; s16x4 v; } A, Bf;                                    \
    A.u[0] = cvtpk_bf16((GQ)*E0, (GQ)*E1);                                 \
    A.u[1] = cvtpk_bf16((GQ)*E2, (GQ)*E3);                                 \
    Bf.u[0] = bx; Bf.u[1] = by;                                            \
    f32x4 d = mfma16(A.v, Bf.v, zero4);                                    \
    bx = cvtpk_bf16(d.x, d.y);                                             \
    by = cvtpk_bf16(d.z, d.w);                                             \
  } while (0)

  int rfull = active >> 2;
  int tail  = active & 3;
  const float* grow = &gT[warp][cl][0];   // 272B-aligned (16 | 272)

  for (int r = 0; r < rfull; ++r) {
    f32x4 g4 = *(const f32x4*)(grow + 4*r);   // one ds_read_b128 per quad
    STEP(g4.x);
    STEP(g4.y);
    STEP(g4.z);
    STEP(g4.w);
  }
  if (tail) {
    f32x4 g4 = *(const f32x4*)(grow + 4*rfull); // staged (t<=63) even past active
    STEP(g4.x);
    if (tail > 1) STEP(g4.y);
    if (tail > 2) STEP(g4.z);
  }
#undef STEP

  Pout[(size_t)(b*16 + c)*64 + lane] = (u32x2){bx, by};
}

// Phase 2: wave per b. v <- P_c * v with power-of-2 renorm; then final lse.
__global__ __launch_bounds__(256) void k_phase2(const u32x2* __restrict__ P,
    const float* __restrict__ trans, const float* __restrict__ lenw,
    const float* __restrict__ Sw, const int* __restrict__ y0,
    float* __restrict__ out){
  __shared__ float red[4];
  int b = blockIdx.x*4 + (threadIdx.x >> 6);
  int lane = threadIdx.x & 63;
  int cl = lane & 15, grp = lane >> 4;
  int len = (int)(lenw[b] + 0.5f);
  float v = (cl == 1) ? 1.f : 0.f;    // exp(Z0): one-hot at SOS_IDX=1
  float lsc = 0.f;                    // accumulated log2 scale
  int nch = (len + 63) >> 6;
  const u32x2* Pb = P + (size_t)b*16*64;
  int srcaddr = (cl >> 2) << 6;       // bpermute byte addr of lane (cl>>2)*16
  int msel = cl & 3;
  for (int c = 0; c < nch; ++c) {
    u32x2 pw = Pb[c*64 + lane];       // P[grp*4+m, cl] bf16 pairs
    float p0 = __uint_as_float(pw.x << 16);
    float p1 = __uint_as_float(pw.x & 0xffff0000u);
    float p2 = __uint_as_float(pw.y << 16);
    float p3 = __uint_as_float(pw.y & 0xffff0000u);
    float q0 = p0*v, q1 = p1*v, q2 = p2*v, q3 = p3*v;
    #pragma unroll
    for (int mk = 1; mk <= 8; mk <<= 1) {
      q0 += __shfl_xor(q0, mk);
      q1 += __shfl_xor(q1, mk);
      q2 += __shfl_xor(q2, mk);
      q3 += __shfl_xor(q3, mk);
    }
    // q_m = v'[grp*4+m]; rebuild v = v'[cl]
    float t0v = __int_as_float(__builtin_amdgcn_ds_bpermute(srcaddr, __float_as_int(q0)));
    float t1v = __int_as_float(__builtin_amdgcn_ds_bpermute(srcaddr, __float_as_int(q1)));
    float t2v = __int_as_float(__builtin_amdgcn_ds_bpermute(srcaddr, __float_as_int(q2)));
    float t3v = __int_as_float(__builtin_amdgcn_ds_bpermute(srcaddr, __float_as_int(q3)));
    float vn = (msel==0) ? t0v : (msel==1) ? t1v : (msel==2) ? t2v : t3v;
    // renorm by 2^-eb, eb = exponent(max)
    float gm = fmaxf(fmaxf(q0,q1), fmaxf(q2,q3));
    gm = fmaxf(gm, __shfl_xor(gm, 16));
    gm = fmaxf(gm, __shfl_xor(gm, 32));
    int eb = (int)((__float_as_uint(gm) >> 23) & 0xff) - 127;
    float sc = __uint_as_float((u32)(127 - eb) << 23);
    v = vn * sc;
    lsc += (float)eb;
  }
  // final: lse_i(Z[i] + trans[EOS,i]) ; EOS row = trans[32+i]
  float eE = exp2x(trans[32 + cl] * LOG2E);
  float num = v * eE;
  num += __shfl_xor(num, 1);
  num += __shfl_xor(num, 2);
  num += __shfl_xor(num, 4);
  num += __shfl_xor(num, 8);
  if (lane == 0) {
    // undo: per-active-step 2^-4 (total 4*len in log2) + renorm scales
    float Z = (log2x(num) + lsc + 4.f*(float)len) * LN2;
    int lastTag = y0[(size_t)len*Bsz + b];
    float Sb = Sw[b] + trans[lastTag];     // trans[PAD=0, lastTag]
    red[threadIdx.x >> 6] = (Z - Sb) * (1.f/(float)Bsz);
  }
  __syncthreads();
  if (threadIdx.x == 0) {
    atomicAdd(out, red[0] + red[1] + red[2] + red[3]);
  }
}

extern "C" void kernel_launch(void* const* d_in, const int* in_sizes, int n_in,
                              void* d_out, int out_size, void* d_ws, size_t ws_size,
                              hipStream_t stream) {
  const float* h     = (const float*)d_in[0];
  const int*   y0    = (const int*)d_in[1];
  const float* mask  = (const float*)d_in[2];
  const float* trans = (const float*)d_in[3];
  float* out  = (float*)d_out;
  float* lenw = (float*)d_ws;
  float* Sw   = lenw + Bsz;
  u32x2* P    = (u32x2*)((char*)d_ws + 16384);

  k_zero  <<<16,   256, 0, stream>>>(lenw, Sw, out);
  k_score <<<256,  256, 0, stream>>>(y0, mask, trans, lenw, Sw);
  k_phase1<<<8192, 256, 0, stream>>>(h, trans, lenw, P);
  k_phase2<<<512,  256, 0, stream>>>(P, trans, lenw, Sw, y0, out);
}